// Round 13
// baseline (130.504 us; speedup 1.0000x reference)
//
#include <hip/hip_runtime.h>
#include <hip/hip_bf16.h>

// Problem constants: B=4, T=4096, C=1024, H=16, D=64
#define BB 4
#define TT 4096
#define CC 1024
#define HH 16
#define DD 64

typedef __attribute__((ext_vector_type(8))) short short8;
typedef __attribute__((ext_vector_type(8))) __bf16 bf16x8;
typedef __attribute__((ext_vector_type(4))) float f32x4;

static __device__ __forceinline__ unsigned short f2bf(float f) {
    unsigned int u = __builtin_bit_cast(unsigned int, f);
    unsigned int r = (u + 0x7FFFu + ((u >> 16) & 1u)) >> 16;
    return (unsigned short)r;
}
static __device__ __forceinline__ float bf2f(unsigned short h) {
    return __builtin_bit_cast(float, ((unsigned int)h) << 16);
}

// ---------------- fp32 -> bf16 conversion ----------------
__global__ void k_f32_to_bf16(const float* __restrict__ src,
                              unsigned short* __restrict__ dst, int n4) {
    int i = blockIdx.x * 256 + threadIdx.x;
    if (i >= n4) return;
    float4 v = ((const float4*)src)[i];
    ushort4 o;
    o.x = f2bf(v.x); o.y = f2bf(v.y); o.z = f2bf(v.z); o.w = f2bf(v.w);
    ((ushort4*)dst)[i] = o;
}

// ================= 256x256 4-phase (8-phase-template) bf16 GEMM =================
// C[m,n] = sum_k A[m,k]*B[n,k] + bias[n];  A: MxK, B: NxK row-major bf16.
// 8 waves (2M x 4N), per-wave output 128x64. K-tile BK=64 = 2 halves of 32 cols.
// LDS: 2 dbuf x {Ah0,Ah1,Bh0,Bh1} x 16KB = 128KB. Per K-tile, 4 phases:
//   P1: vmcnt(4);bar; read af0-3/bf0-3 @ks0 | stage Ah0(kt+1); bar; 16 MFMA; bar
//   P2:              read af4-7 @ks0       | stage Bh0(kt+1); bar; 16 MFMA;
//       vmcnt(4); bar
//   P3:              read af0-3/bf0-3 @ks1 | stage Ah1(kt+1); bar; 16 MFMA; bar
//   P4:              read af4-7 @ks1       | stage Bh1(kt+1); bar; 16 MFMA;
//       vmcnt(4); bar
// FIFO proof: stage order per tile = Ah0,Bh0,Ah1,Bh1 (2 loads each). At P1(kt)
// outstanding = kt's 4 halves (8); vmcnt(4) drains Ah0,Bh0 (what P1/P2 read).
// At P3: +Ah0,Bh0(kt+1) issued -> 8; vmcnt(4) drains Ah1,Bh1(kt). Never 0.
// Stage targets dbuf p^1 whose readers finished at kt-1's last barrier.
// MODE 0: C written bf16 + fused column sum-of-squares S (B shared).
// MODE 1: C fp32, B is PER-BATCH (Wp' holds attnScale fold): Bbase += b*N*K.
#define GBM 256
#define GBN 256

static __device__ __forceinline__ void stage_tile32(
    const unsigned short* __restrict__ Gbase, unsigned short* lbase,
    int k0, int K, int wave, int lane)
{
    #pragma unroll
    for (int q = 0; q < 2; ++q) {
        int c = (wave * 2 + q) * 64 + lane;
        int r = c >> 2;
        int j = c & 3;
        int srcj = (j - (r >> 1)) & 3;
        const unsigned short* g = Gbase + (size_t)r * K + k0 + srcj * 8;
        __builtin_amdgcn_global_load_lds(
            (const __attribute__((address_space(1))) void*)g,
            (__attribute__((address_space(3))) void*)(lbase + (wave * 2 + q) * 512),
            16, 0, 0);
    }
}

template<int MODE>
__global__ __launch_bounds__(512, 2)
void k_gemm256(const unsigned short* __restrict__ A,
               const unsigned short* __restrict__ B,
               const float* __restrict__ bias,
               void* __restrict__ Cout,
               float* __restrict__ S,
               int M, int N, int K)
{
    // [dbuf][ {Ah0, Ah1, Bh0, Bh1} ][8192 ushorts = 16KB]
    __shared__ unsigned short lds[2][4][8192];   // 128 KB
    const int tid  = threadIdx.x;
    const int wave = tid >> 6;
    const int lane = tid & 63;
    const int wr = wave >> 2;   // 0..1
    const int wc = wave & 3;    // 0..3
    const int fr = lane & 15;
    const int hi = lane >> 4;   // 0..3

    // XCD-aware bijective swizzle (256 blocks, 8 XCDs, chunk=32, bn fastest)
    const int wg  = blockIdx.x;
    const int swz = (wg & 7) * 32 + (wg >> 3);
    const int bn  = swz & 3;
    const int bm  = swz >> 2;
    const int b   = bm >> 4;    // batch (16 bm-tiles per batch)

    const unsigned short* Abase = A + (size_t)(bm * GBM) * K;
    const unsigned short* Bbase = B +
        ((size_t)((MODE == 1 ? b * N : 0) + bn * GBN)) * K;

    const int nt = K >> 6;   // 16 K-tiles of 64

    // per-lane constant read offsets within a 16KB half (ushort idx):
    const int sl   = (hi + (fr >> 1)) & 3;
    const int aoff = (wr * 128 + fr) * 32 + sl * 8;   // + mi*512
    const int boff = (wc * 64 + fr) * 32 + sl * 8;    // + ni*512

    f32x4 acc[8][4] = {};

    // ---- prologue: stage K-tile 0 into dbuf 0 (order: Ah0,Bh0,Ah1,Bh1) ----
    stage_tile32(Abase, &lds[0][0][0], 0,  K, wave, lane);
    stage_tile32(Bbase, &lds[0][2][0], 0,  K, wave, lane);
    stage_tile32(Abase, &lds[0][1][0], 32, K, wave, lane);
    stage_tile32(Bbase, &lds[0][3][0], 32, K, wave, lane);

    for (int kt = 0; kt < nt; ++kt) {
        const int p = kt & 1;
        int kn = kt + 1; if (kn >= nt) kn = nt - 1;
        const int kb = kn << 6;

        short8 af[4], bfr[4];

        // ================= P1: ks0, mi 0-3 =================
        asm volatile("s_waitcnt vmcnt(4)" ::: "memory");   // Ah0,Bh0 of kt landed
        __builtin_amdgcn_s_barrier();
        #pragma unroll
        for (int i = 0; i < 4; ++i) bfr[i] = *(const short8*)&lds[p][2][boff + i * 512];
        #pragma unroll
        for (int i = 0; i < 4; ++i) af[i]  = *(const short8*)&lds[p][0][aoff + i * 512];
        stage_tile32(Abase, &lds[p ^ 1][0][0], kb, K, wave, lane);     // Ah0(kt+1)
        __builtin_amdgcn_s_barrier();
        __builtin_amdgcn_s_setprio(1);
        #pragma unroll
        for (int mi = 0; mi < 4; ++mi)
            #pragma unroll
            for (int ni = 0; ni < 4; ++ni)
                acc[mi][ni] = __builtin_amdgcn_mfma_f32_16x16x32_bf16(
                    __builtin_bit_cast(bf16x8, af[mi]),
                    __builtin_bit_cast(bf16x8, bfr[ni]), acc[mi][ni], 0, 0, 0);
        __builtin_amdgcn_s_setprio(0);
        __builtin_amdgcn_s_barrier();

        // ================= P2: ks0, mi 4-7 (bfr reused) =================
        #pragma unroll
        for (int i = 0; i < 4; ++i) af[i] = *(const short8*)&lds[p][0][aoff + (4 + i) * 512];
        stage_tile32(Bbase, &lds[p ^ 1][2][0], kb, K, wave, lane);     // Bh0(kt+1)
        __builtin_amdgcn_s_barrier();
        __builtin_amdgcn_s_setprio(1);
        #pragma unroll
        for (int mi = 0; mi < 4; ++mi)
            #pragma unroll
            for (int ni = 0; ni < 4; ++ni)
                acc[4 + mi][ni] = __builtin_amdgcn_mfma_f32_16x16x32_bf16(
                    __builtin_bit_cast(bf16x8, af[mi]),
                    __builtin_bit_cast(bf16x8, bfr[ni]), acc[4 + mi][ni], 0, 0, 0);
        __builtin_amdgcn_s_setprio(0);
        asm volatile("s_waitcnt vmcnt(4)" ::: "memory");   // Ah1,Bh1 of kt landed
        __builtin_amdgcn_s_barrier();

        // ================= P3: ks1, mi 0-3 =================
        #pragma unroll
        for (int i = 0; i < 4; ++i) bfr[i] = *(const short8*)&lds[p][3][boff + i * 512];
        #pragma unroll
        for (int i = 0; i < 4; ++i) af[i]  = *(const short8*)&lds[p][1][aoff + i * 512];
        stage_tile32(Abase, &lds[p ^ 1][1][0], kb + 32, K, wave, lane); // Ah1(kt+1)
        __builtin_amdgcn_s_barrier();
        __builtin_amdgcn_s_setprio(1);
        #pragma unroll
        for (int mi = 0; mi < 4; ++mi)
            #pragma unroll
            for (int ni = 0; ni < 4; ++ni)
                acc[mi][ni] = __builtin_amdgcn_mfma_f32_16x16x32_bf16(
                    __builtin_bit_cast(bf16x8, af[mi]),
                    __builtin_bit_cast(bf16x8, bfr[ni]), acc[mi][ni], 0, 0, 0);
        __builtin_amdgcn_s_setprio(0);
        __builtin_amdgcn_s_barrier();

        // ================= P4: ks1, mi 4-7 (bfr reused) =================
        #pragma unroll
        for (int i = 0; i < 4; ++i) af[i] = *(const short8*)&lds[p][1][aoff + (4 + i) * 512];
        stage_tile32(Bbase, &lds[p ^ 1][3][0], kb + 32, K, wave, lane); // Bh1(kt+1)
        __builtin_amdgcn_s_barrier();
        __builtin_amdgcn_s_setprio(1);
        #pragma unroll
        for (int mi = 0; mi < 4; ++mi)
            #pragma unroll
            for (int ni = 0; ni < 4; ++ni)
                acc[4 + mi][ni] = __builtin_amdgcn_mfma_f32_16x16x32_bf16(
                    __builtin_bit_cast(bf16x8, af[mi]),
                    __builtin_bit_cast(bf16x8, bfr[ni]), acc[4 + mi][ni], 0, 0, 0);
        __builtin_amdgcn_s_setprio(0);
        __builtin_amdgcn_s_barrier();
    }

    __syncthreads();   // full drain (vmcnt+lgkmcnt) before LDS reuse

    // ---- epilogue: C/D layout col=lane&15, row=(lane>>4)*4+j ----
    const int cg = fr;
    const int rg = hi * 4;
    float* sblk = (float*)&lds[0][0][0];
    if (MODE == 0) {
        if (tid < GBN) sblk[tid] = 0.f;
        __syncthreads();
    }
    float csum[4] = {};
    #pragma unroll
    for (int mi = 0; mi < 8; ++mi) {
        #pragma unroll
        for (int ni = 0; ni < 4; ++ni) {
            int col = bn * GBN + wc * 64 + ni * 16 + cg;
            float bv = bias[col];
            #pragma unroll
            for (int j = 0; j < 4; ++j) {
                int row = bm * GBM + wr * 128 + mi * 16 + rg + j;
                float v = acc[mi][ni][j] + bv;
                if (MODE == 0) {
                    ((unsigned short*)Cout)[(size_t)row * N + col] = f2bf(v);
                    csum[ni] += v * v;
                } else {
                    ((float*)Cout)[(size_t)row * N + col] = v;
                }
            }
        }
    }
    if (MODE == 0) {
        #pragma unroll
        for (int ni = 0; ni < 4; ++ni)
            atomicAdd(&sblk[wc * 64 + ni * 16 + cg], csum[ni]);
        __syncthreads();
        if (tid < GBN) atomicAdd(&S[b * CC + bn * GBN + tid], sblk[tid]);
    }
}

// ------- per-row softmax over heads + IN-PLACE y = bf16(-(w*Pi)) -------
__global__ __launch_bounds__(256)
void k_row_softmax(unsigned short* __restrict__ w16, const float* __restrict__ S,
                   const float* __restrict__ temp,
                   float* __restrict__ dotsU, float* __restrict__ sumPi)
{
    __shared__ float dots_local[CC];
    __shared__ float sPi_local[HH];
    const int tid  = threadIdx.x;
    const int wave = tid >> 6;
    const int lane = tid & 63;
    const int bb   = blockIdx.x >> 7;
    const int tile = blockIdx.x & 127;

    for (int c = tid; c < CC; c += 256) dots_local[c] = 0.f;
    if (tid < HH) sPi_local[tid] = 0.f;
    __syncthreads();

    const int g3 = lane >> 3;
    const int li = lane & 7;

    float inv[2][8], tsc[2];
    #pragma unroll
    for (int q = 0; q < 2; ++q) {
        int c = q * 512 + lane * 8;
        const float4* sp = (const float4*)&S[bb * CC + c];
        float4 s0 = sp[0], s1 = sp[1];
        inv[q][0] = 1.f / fmaxf(s0.x, 1e-24f); inv[q][1] = 1.f / fmaxf(s0.y, 1e-24f);
        inv[q][2] = 1.f / fmaxf(s0.z, 1e-24f); inv[q][3] = 1.f / fmaxf(s0.w, 1e-24f);
        inv[q][4] = 1.f / fmaxf(s1.x, 1e-24f); inv[q][5] = 1.f / fmaxf(s1.y, 1e-24f);
        inv[q][6] = 1.f / fmaxf(s1.z, 1e-24f); inv[q][7] = 1.f / fmaxf(s1.w, 1e-24f);
        tsc[q] = temp[q * 8 + g3];
    }

    float dacc[2][8] = {};
    float sPiAcc[2] = {};

    for (int i = 0; i < 8; ++i) {
        int t = tile * 32 + wave * 8 + i;
        unsigned short* row = w16 + ((size_t)bb * TT + t) * CC;
        float wf[2][8];
        float pq[2];
        #pragma unroll
        for (int q = 0; q < 2; ++q) {
            short8 v = *(const short8*)&row[q * 512 + lane * 8];
            float s = 0.f;
            #pragma unroll
            for (int j = 0; j < 8; ++j) {
                wf[q][j] = bf2f((unsigned short)v[j]);
                s += wf[q][j] * wf[q][j] * inv[q][j];
            }
            pq[q] = s;
        }
        #pragma unroll
        for (int off = 1; off < 8; off <<= 1) {
            pq[0] += __shfl_xor(pq[0], off);
            pq[1] += __shfl_xor(pq[1], off);
        }
        pq[0] *= tsc[0]; pq[1] *= tsc[1];
        float mx = fmaxf(pq[0], pq[1]);
        mx = fmaxf(mx, __shfl_xor(mx, 8));
        mx = fmaxf(mx, __shfl_xor(mx, 16));
        mx = fmaxf(mx, __shfl_xor(mx, 32));
        float e0 = __expf(pq[0] - mx), e1 = __expf(pq[1] - mx);
        float ss = e0 + e1;
        ss += __shfl_xor(ss, 8);
        ss += __shfl_xor(ss, 16);
        ss += __shfl_xor(ss, 32);
        float rs = 1.f / ss;
        float piv[2] = { e0 * rs, e1 * rs };
        #pragma unroll
        for (int q = 0; q < 2; ++q) {
            short8 yo;
            #pragma unroll
            for (int j = 0; j < 8; ++j) {
                dacc[q][j] += piv[q] * wf[q][j] * wf[q][j];
                yo[j] = (short)f2bf(-wf[q][j] * piv[q]);
            }
            *(short8*)&row[q * 512 + lane * 8] = yo;   // in-place y = -(w*Pi)
            if (li == 0) sPiAcc[q] += piv[q];
        }
    }

    #pragma unroll
    for (int q = 0; q < 2; ++q) {
        int c = q * 512 + lane * 8;
        #pragma unroll
        for (int j = 0; j < 8; ++j)
            atomicAdd(&dots_local[c + j], dacc[q][j]);
        if (li == 0) atomicAdd(&sPi_local[q * 8 + g3], sPiAcc[q]);
    }
    __syncthreads();
    for (int c = tid; c < CC; c += 256) atomicAdd(&dotsU[bb * CC + c], dots_local[c]);
    if (tid < HH) atomicAdd(&sumPi[bb * HH + tid], sPi_local[tid]);
}

// -- Wp'[b,n,c] = bf16( Wp[n,c] * (+1/(1 + dotsU[b,c]/(sumPi[b,h]+1e-8))) ) --
// (sign: y already carries the minus)
__global__ void k_scale_wproj(const float* __restrict__ Wp,
                              const float* __restrict__ dotsU,
                              const float* __restrict__ sumPi,
                              unsigned short* __restrict__ out)
{
    int i = blockIdx.x * 256 + threadIdx.x;   // 1,048,576 groups of 4
    int bq  = i >> 18;                        // batch
    int rem = i & 262143;
    int n   = rem >> 8;
    int cg  = (rem & 255) * 4;
    float4 wv = *(const float4*)&Wp[n * CC + cg];
    float4 du = *(const float4*)&dotsU[bq * CC + cg];
    float sp = sumPi[bq * HH + (cg >> 6)] + 1e-8f;
    float a0 = 1.f / (1.f + du.x / sp);
    float a1 = 1.f / (1.f + du.y / sp);
    float a2 = 1.f / (1.f + du.z / sp);
    float a3 = 1.f / (1.f + du.w / sp);
    ushort4 o;
    o.x = f2bf(wv.x * a0); o.y = f2bf(wv.y * a1);
    o.z = f2bf(wv.z * a2); o.w = f2bf(wv.w * a3);
    *(ushort4*)&out[((size_t)bq * CC + n) * CC + cg] = o;
}

// ---------------- launch ----------------
extern "C" void kernel_launch(void* const* d_in, const int* in_sizes, int n_in,
                              void* d_out, int out_size, void* d_ws, size_t ws_size,
                              hipStream_t stream) {
    const float* x      = (const float*)d_in[0];
    const float* W_attn = (const float*)d_in[1];
    const float* b_attn = (const float*)d_in[2];
    const float* W_proj = (const float*)d_in[3];
    const float* b_proj = (const float*)d_in[4];
    const float* temp   = (const float*)d_in[5];

    // xb (x as bf16, 32MB) lives in the FIRST HALF of d_out: fully dead before
    // GEMM2 overwrites d_out with the fp32 result.
    unsigned short* xb = (unsigned short*)d_out;

    char* ws = (char*)d_ws;
    unsigned short* w16   = (unsigned short*)(ws);             // 33554432 B (w, then y in-place)
    unsigned short* Wa16  = (unsigned short*)(ws + 33554432);  // 2097152 B
    unsigned short* Wp16b = (unsigned short*)(ws + 35651584);  // 8388608 B (per-batch Wp')
    float* S     = (float*)(ws + 44040192);  // 16384 B
    float* dotsU = (float*)(ws + 44056576);  // 16384 B
    float* sumPi = (float*)(ws + 44072960);  // 256 B

    // conversions
    k_f32_to_bf16<<<dim3(16384), dim3(256), 0, stream>>>(x, xb, 4194304);
    k_f32_to_bf16<<<dim3(1024), dim3(256), 0, stream>>>(W_attn, Wa16, 262144);

    // zero accumulators (S, dotsU, sumPi contiguous)
    hipMemsetAsync(S, 0, 16384 + 16384 + 256, stream);

    // GEMM1: w16 = bf16(xb @ Wa^T + b_attn); fused S[b,c] = sum_t w^2
    k_gemm256<0><<<dim3(256), dim3(512), 0, stream>>>(
        xb, Wa16, b_attn, w16, S, BB * TT, CC, CC);

    // head-softmax per token; in-place w16 <- bf16(-(w*Pi)); dotsU, sumPi
    k_row_softmax<<<dim3(512), dim3(256), 0, stream>>>(w16, S, temp, dotsU, sumPi);

    // per-batch projection weights with attn fold: Wp'[b] = attn ⊙ Wp
    k_scale_wproj<<<dim3(4096), dim3(256), 0, stream>>>(W_proj, dotsU, sumPi, Wp16b);

    // GEMM2: out = y @ Wp'[b]^T + b_proj (fp32, overwrites xb region of d_out)
    k_gemm256<1><<<dim3(256), dim3(512), 0, stream>>>(
        w16, Wp16b, b_proj, d_out, nullptr, BB * TT, CC, CC);
}